// Round 7
// baseline (307.846 us; speedup 1.0000x reference)
//
#include <hip/hip_runtime.h>
#include <hip/hip_bf16.h>

#define NB     16384   // batch
#define NR     2048    // memory rows
#define NC     128     // memory cols (= key dim)
#define KCTRL  1024    // controller dim
#define EPSF   1e-16f
#define ESTR   2056    // E_s row stride (bf16)
#define R1ROWS 64      // fc_gemm batch rows per block (R7: was 32)

typedef __attribute__((ext_vector_type(8))) short bf16x8;
typedef __attribute__((ext_vector_type(4))) float f32x4;

__device__ __forceinline__ float softplus_f(float x) {
    return fmaxf(x, 0.f) + log1pf(__expf(-fabsf(x)));
}
__device__ __forceinline__ unsigned short f2bf(float f) {
    __hip_bfloat16 h = __float2bfloat16(f);
    return *(unsigned short*)&h;
}
__device__ __forceinline__ float bf2f(unsigned short u) {
    __hip_bfloat16 h;
    *(unsigned short*)&h = u;
    return __bfloat162float(h);
}

// Fragment-order swizzle: element (row n, col k), tiled 16 rows x 32 cols, so
// one wave's 16x32 fragment is 64 lanes x 8 bf16 contiguous (1 KB).
__device__ __forceinline__ size_t swz(int n, int k, int nch) {
    return ((size_t)((n >> 4) * nch + (k >> 5)) * 64 + ((k >> 3) & 3) * 16 + (n & 15)) * 8 + (k & 7);
}

// ---------------- P: merged prep (blocks 0..2047: M; 2048..3071: W) ----------
__global__ __launch_bounds__(64) void prep_all(const float* __restrict__ M,
                                               unsigned short* __restrict__ Mb_sw,
                                               unsigned short* __restrict__ Mt_sw,
                                               float* __restrict__ imn,
                                               const float* __restrict__ W,
                                               unsigned short* __restrict__ Wt_sw) {
    const int bid = blockIdx.x;
    const int l = threadIdx.x;
    if (bid < NR) {
        const int i = bid;
        const float v0 = M[(size_t)i * NC + l];
        const float v1 = M[(size_t)i * NC + 64 + l];
        Mb_sw[swz(i, l, 4)]      = f2bf(v0);
        Mb_sw[swz(i, 64 + l, 4)] = f2bf(v1);
        Mt_sw[swz(l, i, 64)]      = f2bf(v0);
        Mt_sw[swz(64 + l, i, 64)] = f2bf(v1);
        float s = v0 * v0 + v1 * v1;
        #pragma unroll
        for (int m = 1; m < 64; m <<= 1) s += __shfl_xor(s, m);
        if (l == 0) imn[i] = 1.f / sqrtf(s);
    } else {
        const int k = bid - NR;   // 0..1023
        Wt_sw[swz(l, k, 32)]      = f2bf(W[(size_t)k * 134 + l]);
        Wt_sw[swz(64 + l, k, 32)] = f2bf(W[(size_t)k * 134 + 64 + l]);
        if (l < 6) {
            Wt_sw[swz(128 + l, k, 32)] = f2bf(W[(size_t)k * 134 + 128 + l]);
        }
    }
}

// ---------------- K1: fc GEMM rewrite (R7) -----------------------------------
// R6's fc (~48us inferred) was a barrier-paced HBM-latency chain: 32-row
// tiles, 8 barrier pairs, 2 loads in flight vs ~900cy HBM latency. R7:
// 64 rows x 512 thr, grid=256 (1 block/CU, full GPU), K in 8 chunks of 128,
// REGISTER-staged x (4 float4/thread issued right after the barrier, consumed
// a full MFMA region later -> latency hidden), wave (rg=w>>1, half=w&1) owns
// rows rg*16..+15 and col tiles {half*4..+3} (+tile 8 for half 0). Per-tile
// K order identical to the verified kernels (sg=0..31 sequential) -> kb
// bit-identical; ksum now a deterministic tile-order sum (was atomic-order).
__global__ __launch_bounds__(512) void fc_gemm(const float* __restrict__ x,
                                               const unsigned short* __restrict__ Wt_sw,
                                               const float* __restrict__ bfc,
                                               unsigned short* __restrict__ kb,
                                               float* __restrict__ scal_g) {
    __shared__ __align__(16) unsigned short x_s[R1ROWS][136];  // 17408 B
    __shared__ float wred[R1ROWS][2];
    __shared__ float h6s[R1ROWS][6];

    const int tid  = threadIdx.x;
    const int w    = tid >> 6;
    const int lane = tid & 63;
    const int quad = lane >> 4;
    const int l16  = lane & 15;
    const int rg   = w >> 1;          // row group 0..3 (rows rg*16..+15)
    const int half = w & 1;           // col-tile half
    const int tb   = half * 4;        // tile base: 0 or 4
    const int b0   = blockIdx.x * R1ROWS;

    f32x4 acc0 = {0.f, 0.f, 0.f, 0.f};
    f32x4 acc1 = {0.f, 0.f, 0.f, 0.f};
    f32x4 acc2 = {0.f, 0.f, 0.f, 0.f};
    f32x4 acc3 = {0.f, 0.f, 0.f, 0.f};
    f32x4 accH = {0.f, 0.f, 0.f, 0.f};
    const unsigned short* wb = Wt_sw + lane * 8;

    // preload chunk 0 into registers (64 rows x 128 cols f32 = 2048 float4)
    float4 st0, st1, st2, st3;
    {
        const int r0 = tid >> 5, c4 = (tid & 31) * 4;
        const float* xp = x + (size_t)(b0 + r0) * KCTRL + c4;
        st0 = *(const float4*)(xp);
        st1 = *(const float4*)(xp + 16 * KCTRL);
        st2 = *(const float4*)(xp + 32 * KCTRL);
        st3 = *(const float4*)(xp + 48 * KCTRL);
    }

    for (int kc = 0; kc < 8; kc++) {
        // stage registers -> LDS bf16
        {
            const int r0 = tid >> 5, c4 = (tid & 31) * 4;
            unsigned short* d0 = &x_s[r0][c4];
            d0[0] = f2bf(st0.x); d0[1] = f2bf(st0.y); d0[2] = f2bf(st0.z); d0[3] = f2bf(st0.w);
            unsigned short* d1 = &x_s[r0 + 16][c4];
            d1[0] = f2bf(st1.x); d1[1] = f2bf(st1.y); d1[2] = f2bf(st1.z); d1[3] = f2bf(st1.w);
            unsigned short* d2 = &x_s[r0 + 32][c4];
            d2[0] = f2bf(st2.x); d2[1] = f2bf(st2.y); d2[2] = f2bf(st2.z); d2[3] = f2bf(st2.w);
            unsigned short* d3 = &x_s[r0 + 48][c4];
            d3[0] = f2bf(st3.x); d3[1] = f2bf(st3.y); d3[2] = f2bf(st3.z); d3[3] = f2bf(st3.w);
        }
        __syncthreads();
        if (kc < 7) {     // issue next chunk's loads early (hide under MFMAs)
            const int r0 = tid >> 5, c4 = (tid & 31) * 4;
            const float* xp = x + (size_t)(b0 + r0) * KCTRL + (kc + 1) * 128 + c4;
            st0 = *(const float4*)(xp);
            st1 = *(const float4*)(xp + 16 * KCTRL);
            st2 = *(const float4*)(xp + 32 * KCTRL);
            st3 = *(const float4*)(xp + 48 * KCTRL);
        }
        #pragma unroll
        for (int ks = 0; ks < 4; ks++) {
            const int sg = kc * 4 + ks;     // global K-step 0..31
            const bf16x8 a  = *(const bf16x8*)&x_s[rg * 16 + l16][ks * 32 + quad * 8];
            const bf16x8 b0v = *(const bf16x8*)(wb + (size_t)((tb + 0) * 32 + sg) * 512);
            const bf16x8 b1v = *(const bf16x8*)(wb + (size_t)((tb + 1) * 32 + sg) * 512);
            const bf16x8 b2v = *(const bf16x8*)(wb + (size_t)((tb + 2) * 32 + sg) * 512);
            const bf16x8 b3v = *(const bf16x8*)(wb + (size_t)((tb + 3) * 32 + sg) * 512);
            acc0 = __builtin_amdgcn_mfma_f32_16x16x32_bf16(a, b0v, acc0, 0, 0, 0);
            acc1 = __builtin_amdgcn_mfma_f32_16x16x32_bf16(a, b1v, acc1, 0, 0, 0);
            acc2 = __builtin_amdgcn_mfma_f32_16x16x32_bf16(a, b2v, acc2, 0, 0, 0);
            acc3 = __builtin_amdgcn_mfma_f32_16x16x32_bf16(a, b3v, acc3, 0, 0, 0);
            if (half == 0) {
                const bf16x8 bH = *(const bf16x8*)(wb + (size_t)(8 * 32 + sg) * 512);
                accH = __builtin_amdgcn_mfma_f32_16x16x32_bf16(a, bH, accH, 0, 0, 0);
            }
        }
        __syncthreads();
    }

    // epilogue: kb stores + per-row sumsq (wave-local, no atomics) + h6
    float part[4] = {0.f, 0.f, 0.f, 0.f};
    #pragma unroll
    for (int t = 0; t < 4; t++) {
        const f32x4 ac = (t == 0) ? acc0 : (t == 1) ? acc1 : (t == 2) ? acc2 : acc3;
        const float bb = bfc[(tb + t) * 16 + l16];
        #pragma unroll
        for (int reg = 0; reg < 4; reg++) {
            const float v = ac[reg] + bb;
            kb[(size_t)(b0 + rg * 16 + quad * 4 + reg) * NC + (tb + t) * 16 + l16] = f2bf(v);
            part[reg] += v * v;
        }
    }
    #pragma unroll
    for (int s = 1; s < 16; s <<= 1) {
        #pragma unroll
        for (int reg = 0; reg < 4; reg++) part[reg] += __shfl_xor(part[reg], s);
    }
    if (l16 == 0) {
        #pragma unroll
        for (int reg = 0; reg < 4; reg++)
            wred[rg * 16 + quad * 4 + reg][half] = part[reg];
    }
    if (half == 0 && l16 < 6) {
        const float bh = bfc[128 + l16];
        #pragma unroll
        for (int reg = 0; reg < 4; reg++)
            h6s[rg * 16 + quad * 4 + reg][l16] = accH[reg] + bh;
    }
    __syncthreads();

    if (tid < R1ROWS) {
        const float kn = sqrtf(wred[tid][0] + wred[tid][1]);
        const float* h = h6s[tid];
        const float beta = softplus_f(h[0]);
        const float g = 1.f / (1.f + __expf(-h[1]));
        const float m3 = fmaxf(h[2], fmaxf(h[3], h[4]));
        const float e0 = __expf(h[2] - m3), e1 = __expf(h[3] - m3), e2 = __expf(h[4] - m3);
        const float inv = 1.f / (e0 + e1 + e2);
        float* sgp = scal_g + (size_t)(b0 + tid) * 6;
        sgp[0] = beta / kn;
        sgp[1] = g;
        sgp[2] = e0 * inv;
        sgp[3] = e1 * inv;
        sgp[4] = e2 * inv;
        sgp[5] = 1.f + softplus_f(h[5]);
    }
}

// ---------------- K2: head (phases 1 / 1.5 / 2), 512 thr / 16 rows -----------
// VERBATIM from R6 (verified: 94.6us, matched prediction exactly).
__global__ __launch_bounds__(512, 4) void head_ntm(const unsigned short* __restrict__ kb,
                                                   const float* __restrict__ scal_g,
                                                   const unsigned short* __restrict__ Mb_sw,
                                                   const unsigned short* __restrict__ Mt_sw,
                                                   const float* __restrict__ imn,
                                                   const float* __restrict__ wprev,
                                                   float* __restrict__ out) {
    __shared__ __align__(16) unsigned short E_s[16][ESTR];   // 65792 B
    __shared__ float scal_s[16][6];    // {beta/kn, g, s0, s1, s2, gamma}
    __shared__ float wred[16][8];
    __shared__ float fa_s[16], fc_s[16], invZ_s[16];

    const int tid  = threadIdx.x;
    const int w    = tid >> 6;         // 8 waves
    const int lane = tid & 63;
    const int quad = lane >> 4;
    const int l16  = lane & 15;
    const int b0   = blockIdx.x * 16;

    if (tid < 16) {
        const float* sgp = scal_g + (size_t)(b0 + tid) * 6;
        #pragma unroll
        for (int j = 0; j < 6; j++) scal_s[tid][j] = sgp[j];
    }
    __syncthreads();

    // ---- phase 1: E = exp((beta/kn)*(1/mn)*(k . M_i)), distance-2 prefetch --
    {
        float cbs[4];
        #pragma unroll
        for (int reg = 0; reg < 4; reg++) cbs[reg] = scal_s[quad * 4 + reg][0];

        const unsigned short* kbp = kb + (size_t)(b0 + l16) * NC + quad * 8;
        const bf16x8 af0 = *(const bf16x8*)(kbp);
        const bf16x8 af1 = *(const bf16x8*)(kbp + 32);
        const bf16x8 af2 = *(const bf16x8*)(kbp + 64);
        const bf16x8 af3 = *(const bf16x8*)(kbp + 96);

        const unsigned short* bpw = Mb_sw + (size_t)(w * 16) * 2048 + lane * 8;
        bf16x8 f00 = *(const bf16x8*)(bpw);
        bf16x8 f01 = *(const bf16x8*)(bpw + 512);
        bf16x8 f02 = *(const bf16x8*)(bpw + 1024);
        bf16x8 f03 = *(const bf16x8*)(bpw + 1536);
        bf16x8 f10 = *(const bf16x8*)(bpw + 2048);
        bf16x8 f11 = *(const bf16x8*)(bpw + 2048 + 512);
        bf16x8 f12 = *(const bf16x8*)(bpw + 2048 + 1024);
        bf16x8 f13 = *(const bf16x8*)(bpw + 2048 + 1536);
        float im0 = imn[(w * 16 + 0) * 16 + l16];
        float im1 = imn[(w * 16 + 1) * 16 + l16];

        float Sp[4] = {0.f, 0.f, 0.f, 0.f};
        #pragma unroll
        for (int t = 0; t < 16; t += 2) {
            // ---- even sub-iter: row tile nt = w*16+t, slot 0 ----
            {
                const int nt = w * 16 + t;
                f32x4 aA = {0.f, 0.f, 0.f, 0.f};
                f32x4 aB = {0.f, 0.f, 0.f, 0.f};
                aA = __builtin_amdgcn_mfma_f32_16x16x32_bf16(af0, f00, aA, 0, 0, 0);
                aB = __builtin_amdgcn_mfma_f32_16x16x32_bf16(af2, f02, aB, 0, 0, 0);
                aA = __builtin_amdgcn_mfma_f32_16x16x32_bf16(af1, f01, aA, 0, 0, 0);
                aB = __builtin_amdgcn_mfma_f32_16x16x32_bf16(af3, f03, aB, 0, 0, 0);
                const float imc = im0;
                if (t < 14) {   // prefetch row tile nt+2 into slot 0
                    const unsigned short* bp = Mb_sw + (size_t)(nt + 2) * 2048 + lane * 8;
                    f00 = *(const bf16x8*)(bp);
                    f01 = *(const bf16x8*)(bp + 512);
                    f02 = *(const bf16x8*)(bp + 1024);
                    f03 = *(const bf16x8*)(bp + 1536);
                    im0 = imn[(nt + 2) * 16 + l16];
                }
                const int n0 = nt * 16;
                #pragma unroll
                for (int reg = 0; reg < 4; reg++) {
                    const float e = __expf((aA[reg] + aB[reg]) * cbs[reg] * imc);
                    E_s[quad * 4 + reg][n0 + l16] = f2bf(e);
                    Sp[reg] += e;
                }
            }
            // ---- odd sub-iter: row tile nt = w*16+t+1, slot 1 ----
            {
                const int nt = w * 16 + t + 1;
                f32x4 aA = {0.f, 0.f, 0.f, 0.f};
                f32x4 aB = {0.f, 0.f, 0.f, 0.f};
                aA = __builtin_amdgcn_mfma_f32_16x16x32_bf16(af0, f10, aA, 0, 0, 0);
                aB = __builtin_amdgcn_mfma_f32_16x16x32_bf16(af2, f12, aB, 0, 0, 0);
                aA = __builtin_amdgcn_mfma_f32_16x16x32_bf16(af1, f11, aA, 0, 0, 0);
                aB = __builtin_amdgcn_mfma_f32_16x16x32_bf16(af3, f13, aB, 0, 0, 0);
                const float imc = im1;
                if (t < 13) {   // prefetch row tile nt+2 = w*16+t+3 into slot 1
                    const unsigned short* bp = Mb_sw + (size_t)(nt + 2) * 2048 + lane * 8;
                    f10 = *(const bf16x8*)(bp);
                    f11 = *(const bf16x8*)(bp + 512);
                    f12 = *(const bf16x8*)(bp + 1024);
                    f13 = *(const bf16x8*)(bp + 1536);
                    im1 = imn[(nt + 2) * 16 + l16];
                }
                const int n0 = nt * 16;
                #pragma unroll
                for (int reg = 0; reg < 4; reg++) {
                    const float e = __expf((aA[reg] + aB[reg]) * cbs[reg] * imc);
                    E_s[quad * 4 + reg][n0 + l16] = f2bf(e);
                    Sp[reg] += e;
                }
            }
        }
        #pragma unroll
        for (int s = 1; s < 16; s <<= 1) {
            #pragma unroll
            for (int reg = 0; reg < 4; reg++) Sp[reg] += __shfl_xor(Sp[reg], s);
        }
        if (l16 == 0) {
            #pragma unroll
            for (int reg = 0; reg < 4; reg++) wred[quad * 4 + reg][w] = Sp[reg];
        }
    }
    __syncthreads();
    if (tid < 16) {
        float S = 0.f;
        #pragma unroll
        for (int i = 0; i < 8; i++) S += wred[tid][i];
        const float g = scal_s[tid][1];
        fa_s[tid] = g / S;
        fc_s[tid] = 1.f - g;
    }
    __syncthreads();

    // ---- phase 1.5: parallel shift+pow, in place, software-pipelined ----
    {
        const int row  = tid >> 5;           // 0..15
        const int g    = tid & 31;
        const int base = tid & 32;           // wave-local half base
        const float s0 = scal_s[row][2], s1 = scal_s[row][3], s2 = scal_s[row][4];
        const float gmm = scal_s[row][5];
        const float fa = fa_s[row], fcm = fc_s[row];
        const float* wp = wprev + (size_t)(b0 + row) * NR;

        int c0 = g * 8;
        bf16x8 E8c = *(const bf16x8*)&E_s[row][c0];
        float eLc  = bf2f(E_s[row][(c0 + NR - 1) & (NR - 1)]);
        float eRc  = bf2f(E_s[row][c0 + 8]);
        float4 wac = *(const float4*)(wp + c0);
        float4 wbc = *(const float4*)(wp + c0 + 4);
        float wpLc = wp[(c0 + NR - 1) & (NR - 1)];
        float wpRc = wp[c0 + 8];

        float Zp = 0.f, carry = 0.f, E0sav = 0.f;
        #pragma unroll
        for (int j = 0; j < 8; j++) {
            bf16x8 E8n; float eLn = 0.f, eRn = 0.f, wpLn = 0.f, wpRn = 0.f;
            float4 wan, wbn;
            if (j < 7) {
                const int c1 = c0 + 256;
                E8n  = *(const bf16x8*)&E_s[row][c1];
                eLn  = bf2f(E_s[row][c1 - 1]);
                eRn  = bf2f(E_s[row][(c1 + 8) & (NR - 1)]);
                wan  = *(const float4*)(wp + c1);
                wbn  = *(const float4*)(wp + c1 + 4);
                wpLn = wp[c1 - 1];
                wpRn = wp[(c1 + 8) & (NR - 1)];
            }
            float ef[8];
            #pragma unroll
            for (int i = 0; i < 8; i++) ef[i] = bf2f((unsigned short)E8c[i]);
            if (j == 0) E0sav = __shfl(ef[0], base);
            const float eL = (g == 0 && j > 0) ? carry : eLc;
            const float eR = (g == 31 && j == 7) ? E0sav : eRc;
            carry = __shfl(ef[7], base + 31);

            float wg[10];
            wg[0] = fmaf(fa, eL,    fcm * wpLc);
            wg[1] = fmaf(fa, ef[0], fcm * wac.x);
            wg[2] = fmaf(fa, ef[1], fcm * wac.y);
            wg[3] = fmaf(fa, ef[2], fcm * wac.z);
            wg[4] = fmaf(fa, ef[3], fcm * wac.w);
            wg[5] = fmaf(fa, ef[4], fcm * wbc.x);
            wg[6] = fmaf(fa, ef[5], fcm * wbc.y);
            wg[7] = fmaf(fa, ef[6], fcm * wbc.z);
            wg[8] = fmaf(fa, ef[7], fcm * wbc.w);
            wg[9] = fmaf(fa, eR,    fcm * wpRc);

            bf16x8 out8;
            #pragma unroll
            for (int i = 0; i < 8; i++) {
                const float wt = fmaf(s0, wg[i], fmaf(s1, wg[i + 1], s2 * wg[i + 2])) + EPSF;
                const float pw = exp2f(gmm * log2f(wt));   // wt^gamma, wt > 0
                Zp += pw;
                out8[i] = (short)f2bf(pw);
            }
            *(bf16x8*)&E_s[row][c0] = out8;

            c0 += 256;
            E8c = E8n; eLc = eLn; eRc = eRn;
            wac = wan; wbc = wbn; wpLc = wpLn; wpRc = wpRn;
        }
        #pragma unroll
        for (int s = 1; s < 32; s <<= 1) Zp += __shfl_xor(Zp, s);
        if (g == 0) invZ_s[row] = 1.f / Zp;
    }
    __syncthreads();

    // ---- phase 2: r = (w_pow @ M) * invZ, distance-2 Mt_sw prefetch -------
    {
        f32x4 acc0 = {0.f, 0.f, 0.f, 0.f};
        f32x4 acc1 = {0.f, 0.f, 0.f, 0.f};
        f32x4 acc2 = {0.f, 0.f, 0.f, 0.f};
        f32x4 acc3 = {0.f, 0.f, 0.f, 0.f};
        const unsigned short* bp = Mt_sw + (size_t)w * 32768 + lane * 8;
        bf16x8 c00 = *(const bf16x8*)(bp);
        bf16x8 c01 = *(const bf16x8*)(bp + 512);
        bf16x8 c02 = *(const bf16x8*)(bp + 1024);
        bf16x8 c03 = *(const bf16x8*)(bp + 1536);
        bf16x8 c10 = *(const bf16x8*)(bp + 2048);
        bf16x8 c11 = *(const bf16x8*)(bp + 2048 + 512);
        bf16x8 c12 = *(const bf16x8*)(bp + 2048 + 1024);
        bf16x8 c13 = *(const bf16x8*)(bp + 2048 + 1536);

        #pragma unroll
        for (int k0 = 0; k0 < NR; k0 += 256) {
            // ---- even half: A at columns k0..k0+127, B chunks (k0>>5)..+3 --
            {
                const bf16x8 a0 = *(const bf16x8*)&E_s[l16][k0 + quad * 8];
                const bf16x8 a1 = *(const bf16x8*)&E_s[l16][k0 + 32 + quad * 8];
                const bf16x8 a2 = *(const bf16x8*)&E_s[l16][k0 + 64 + quad * 8];
                const bf16x8 a3 = *(const bf16x8*)&E_s[l16][k0 + 96 + quad * 8];
                acc0 = __builtin_amdgcn_mfma_f32_16x16x32_bf16(a0, c00, acc0, 0, 0, 0);
                acc1 = __builtin_amdgcn_mfma_f32_16x16x32_bf16(a1, c01, acc1, 0, 0, 0);
                acc2 = __builtin_amdgcn_mfma_f32_16x16x32_bf16(a2, c02, acc2, 0, 0, 0);
                acc3 = __builtin_amdgcn_mfma_f32_16x16x32_bf16(a3, c03, acc3, 0, 0, 0);
                if (k0 < NR - 256) {   // prefetch chunks for k0+256 into slot 0
                    const unsigned short* np = bp + (size_t)((k0 >> 5) + 8) * 512;
                    c00 = *(const bf16x8*)(np);
                    c01 = *(const bf16x8*)(np + 512);
                    c02 = *(const bf16x8*)(np + 1024);
                    c03 = *(const bf16x8*)(np + 1536);
                }
            }
            // ---- odd half: A at columns k0+128.., B chunks (k0>>5)+4..+7 ---
            {
                const int k1 = k0 + 128;
                const bf16x8 a0 = *(const bf16x8*)&E_s[l16][k1 + quad * 8];
                const bf16x8 a1 = *(const bf16x8*)&E_s[l16][k1 + 32 + quad * 8];
                const bf16x8 a2 = *(const bf16x8*)&E_s[l16][k1 + 64 + quad * 8];
                const bf16x8 a3 = *(const bf16x8*)&E_s[l16][k1 + 96 + quad * 8];
                acc0 = __builtin_amdgcn_mfma_f32_16x16x32_bf16(a0, c10, acc0, 0, 0, 0);
                acc1 = __builtin_amdgcn_mfma_f32_16x16x32_bf16(a1, c11, acc1, 0, 0, 0);
                acc2 = __builtin_amdgcn_mfma_f32_16x16x32_bf16(a2, c12, acc2, 0, 0, 0);
                acc3 = __builtin_amdgcn_mfma_f32_16x16x32_bf16(a3, c13, acc3, 0, 0, 0);
                if (k0 < NR - 384) {   // prefetch chunks for k1+256 into slot 1
                    const unsigned short* np = bp + (size_t)((k0 >> 5) + 12) * 512;
                    c10 = *(const bf16x8*)(np);
                    c11 = *(const bf16x8*)(np + 512);
                    c12 = *(const bf16x8*)(np + 1024);
                    c13 = *(const bf16x8*)(np + 1536);
                }
            }
        }
        #pragma unroll
        for (int reg = 0; reg < 4; reg++) {
            const int m = quad * 4 + reg;
            const float v = (acc0[reg] + acc1[reg]) + (acc2[reg] + acc3[reg]);
            out[(size_t)(b0 + m) * NC + w * 16 + l16] = v * invZ_s[m];
        }
    }
}

extern "C" void kernel_launch(void* const* d_in, const int* in_sizes, int n_in,
                              void* d_out, int out_size, void* d_ws, size_t ws_size,
                              hipStream_t stream) {
    const float* x     = (const float*)d_in[0];
    const float* Wfc   = (const float*)d_in[1];
    const float* bfc   = (const float*)d_in[2];
    const float* M     = (const float*)d_in[3];
    const float* wprev = (const float*)d_in[4];
    float* out = (float*)d_out;

    char* ws = (char*)d_ws;
    float*          imn    = (float*)(ws);                      // 8192 B
    unsigned short* Mb_sw  = (unsigned short*)(ws + 8192);      // 524288 B
    unsigned short* Mt_sw  = (unsigned short*)(ws + 532480);    // 524288 B
    unsigned short* Wt_sw  = (unsigned short*)(ws + 1056768);   // 294912 B
    unsigned short* kb     = (unsigned short*)(ws + 1351680);   // 4194304 B
    float*          scal_g = (float*)(ws + 5545984);            // 393216 B

    hipLaunchKernelGGL(prep_all, dim3(NR + KCTRL), dim3(64), 0, stream,
                       M, Mb_sw, Mt_sw, imn, Wfc, Wt_sw);
    hipLaunchKernelGGL(fc_gemm, dim3(NB / R1ROWS), dim3(512), 0, stream,
                       x, Wt_sw, bfc, kb, scal_g);
    hipLaunchKernelGGL(head_ntm, dim3(NB / 16), dim3(512), 0, stream,
                       kb, scal_g, Mb_sw, Mt_sw, imn, wprev, out);
}

// Round 8
// 289.748 us; speedup vs baseline: 1.0625x; 1.0625x over previous
//
#include <hip/hip_runtime.h>
#include <hip/hip_bf16.h>

#define NB    16384   // batch
#define NR    2048    // memory rows
#define NC    128     // memory cols (= key dim)
#define KCTRL 1024    // controller dim
#define EPSF  1e-16f
#define ESTR  2056    // E_s row stride (bf16)
#define XSTR  1032    // x-stage row stride (bf16), overlays E_s

typedef __attribute__((ext_vector_type(8))) short bf16x8;
typedef __attribute__((ext_vector_type(4))) float f32x4;

__device__ __forceinline__ float softplus_f(float x) {
    return fmaxf(x, 0.f) + log1pf(__expf(-fabsf(x)));
}
__device__ __forceinline__ unsigned short f2bf(float f) {
    __hip_bfloat16 h = __float2bfloat16(f);
    return *(unsigned short*)&h;
}
__device__ __forceinline__ float bf2f(unsigned short u) {
    __hip_bfloat16 h;
    *(unsigned short*)&h = u;
    return __bfloat162float(h);
}

// Fragment-order swizzle: element (row n, col k), tiled 16 rows x 32 cols, so
// one wave's 16x32 fragment is 64 lanes x 8 bf16 contiguous (1 KB).
__device__ __forceinline__ size_t swz(int n, int k, int nch) {
    return ((size_t)((n >> 4) * nch + (k >> 5)) * 64 + ((k >> 3) & 3) * 16 + (n & 15)) * 8 + (k & 7);
}

// ---------------- P: merged prep (blocks 0..2047: M; 2048..3071: W) ----------
__global__ __launch_bounds__(64) void prep_all(const float* __restrict__ M,
                                               unsigned short* __restrict__ Mb_sw,
                                               unsigned short* __restrict__ Mt_sw,
                                               float* __restrict__ imn,
                                               const float* __restrict__ W,
                                               unsigned short* __restrict__ Wt_sw) {
    const int bid = blockIdx.x;
    const int l = threadIdx.x;
    if (bid < NR) {
        const int i = bid;
        const float v0 = M[(size_t)i * NC + l];
        const float v1 = M[(size_t)i * NC + 64 + l];
        Mb_sw[swz(i, l, 4)]      = f2bf(v0);
        Mb_sw[swz(i, 64 + l, 4)] = f2bf(v1);
        Mt_sw[swz(l, i, 64)]      = f2bf(v0);
        Mt_sw[swz(64 + l, i, 64)] = f2bf(v1);
        float s = v0 * v0 + v1 * v1;
        #pragma unroll
        for (int m = 1; m < 64; m <<= 1) s += __shfl_xor(s, m);
        if (l == 0) imn[i] = 1.f / sqrtf(s);
    } else {
        const int k = bid - NR;   // 0..1023
        Wt_sw[swz(l, k, 32)]      = f2bf(W[(size_t)k * 134 + l]);
        Wt_sw[swz(64 + l, k, 32)] = f2bf(W[(size_t)k * 134 + 64 + l]);
        if (l < 6) {
            Wt_sw[swz(128 + l, k, 32)] = f2bf(W[(size_t)k * 134 + 128 + l]);
        }
    }
}

// ---------------- Fused: fc + head, 512 threads / 16 batch rows --------------
// R13 = R3 (verified 128.6us) + ONE change: phase 1.5's wprev stream moved to
// a register pipeline. R5 ablation: residual bucket ~44us; wprev (128MB total,
// largest input) was fetched INSIDE the serialized p1.5 window with depth-1/2
// prefetch + 2 scalar edge loads per chunk. Now: chunks j=0..3 hoisted into
// 32 VGPRs at kernel entry (HBM latency hides under stage A + fc + p1);
// chunks 4..7 prefetched in-loop at distance 4 (static slot rotation under
// full unroll); ALL edge scalars replaced by __shfl of neighbor lanes' chunks
// (same floats -> bit-identical output). R6/R7 lesson: 3-kernel split is a
// net loss (total 305-308 vs 290.5 fused) -> reverted to fused.
__global__ __launch_bounds__(512, 4) void fused_ntm(const float* __restrict__ x,
                                                    const unsigned short* __restrict__ Wt_sw,
                                                    const float* __restrict__ bfc,
                                                    const unsigned short* __restrict__ Mb_sw,
                                                    const unsigned short* __restrict__ Mt_sw,
                                                    const float* __restrict__ imn,
                                                    const float* __restrict__ wprev,
                                                    float* __restrict__ out) {
    __shared__ __align__(16) unsigned short E_s[16][ESTR];   // 65792 B (x_s overlay)
    __shared__ __align__(16) unsigned short k_s[16][136];    // 4352 B
    __shared__ float h6s[16][6];
    __shared__ float ksum[16];
    __shared__ float scal_s[16][6];    // {beta/kn, g, s0, s1, s2, gamma}
    __shared__ float wred[16][8];
    __shared__ float fa_s[16], fc_s[16], invZ_s[16];

    unsigned short (*x_s)[XSTR] = (unsigned short(*)[XSTR])E_s;

    const int tid  = threadIdx.x;
    const int w    = tid >> 6;         // 8 waves
    const int lane = tid & 63;
    const int quad = lane >> 4;
    const int l16  = lane & 15;
    const int b0   = blockIdx.x * 16;

    if (tid < 16) ksum[tid] = 0.f;

    // ---- stage A: x (16x1024 f32) -> LDS bf16, coalesced ----
    #pragma unroll
    for (int p = 0; p < 8; p++) {
        const int idx = p * 512 + tid;          // float4 index, 4096 total
        const int row = idx >> 8;
        const int c4  = idx & 255;
        const float4 v = *(const float4*)(x + (size_t)(b0 + row) * KCTRL + c4 * 4);
        unsigned short* d = &x_s[row][c4 * 4];
        d[0] = f2bf(v.x); d[1] = f2bf(v.y); d[2] = f2bf(v.z); d[3] = f2bf(v.w);
    }

    // ---- wprev entry hoist (p1.5 identity): chunks j=0..3 -> 32 VGPR.
    //      Issued after x loads (younger in vmcnt order); latency hides under
    //      stage A + fc + phase 1. ----
    const int prow  = tid >> 5;          // 0..15
    const int pg    = tid & 31;
    const int pbase = tid & 32;          // wave-local half base
    const int pc0   = pg * 8;
    const float* wp = wprev + (size_t)(b0 + prow) * NR;
    float4 wva[4], wvb[4];
    #pragma unroll
    for (int j = 0; j < 4; j++) {
        wva[j] = *(const float4*)(wp + pc0 + j * 256);
        wvb[j] = *(const float4*)(wp + pc0 + j * 256 + 4);
    }
    const float wpL0 = wp[(pc0 + NR - 1) & (NR - 1)];
    __syncthreads();

    // ---- stage B: h = x@W + b. Wave w -> col tile w; wave 0 also tile 8. ----
    {
        f32x4 accF = {0.f, 0.f, 0.f, 0.f};
        f32x4 accH = {0.f, 0.f, 0.f, 0.f};
        const unsigned short* wbp = Wt_sw + (size_t)w * 16384 + lane * 8;
        const unsigned short* whp = Wt_sw + (size_t)8 * 16384 + lane * 8;
        bf16x8 bc0 = *(const bf16x8*)(wbp);
        bf16x8 bc1 = *(const bf16x8*)(wbp + 512);
        #pragma unroll
        for (int i = 0; i < 32; i += 2) {
            bf16x8 bn0, bn1;
            if (i < 30) {
                bn0 = *(const bf16x8*)(wbp + (size_t)(i + 2) * 512);
                bn1 = *(const bf16x8*)(wbp + (size_t)(i + 3) * 512);
            }
            const bf16x8 a0 = *(const bf16x8*)&x_s[l16][i * 32 + quad * 8];
            const bf16x8 a1 = *(const bf16x8*)&x_s[l16][(i + 1) * 32 + quad * 8];
            accF = __builtin_amdgcn_mfma_f32_16x16x32_bf16(a0, bc0, accF, 0, 0, 0);
            accF = __builtin_amdgcn_mfma_f32_16x16x32_bf16(a1, bc1, accF, 0, 0, 0);
            if (w == 0) {
                const bf16x8 h0 = *(const bf16x8*)(whp + (size_t)i * 512);
                const bf16x8 h1 = *(const bf16x8*)(whp + (size_t)(i + 1) * 512);
                accH = __builtin_amdgcn_mfma_f32_16x16x32_bf16(a0, h0, accH, 0, 0, 0);
                accH = __builtin_amdgcn_mfma_f32_16x16x32_bf16(a1, h1, accH, 0, 0, 0);
            }
            bc0 = bn0; bc1 = bn1;
        }
        __syncthreads();          // x_s reads done (E_s overlay safe later)

        const float bb = bfc[w * 16 + l16];
        float part[4];
        #pragma unroll
        for (int reg = 0; reg < 4; reg++) {
            const int m = quad * 4 + reg;
            const float v = accF[reg] + bb;
            k_s[m][w * 16 + l16] = f2bf(v);
            part[reg] = v * v;
        }
        #pragma unroll
        for (int s = 1; s < 16; s <<= 1) {
            #pragma unroll
            for (int reg = 0; reg < 4; reg++) part[reg] += __shfl_xor(part[reg], s);
        }
        if (l16 == 0) {
            #pragma unroll
            for (int reg = 0; reg < 4; reg++) atomicAdd(&ksum[quad * 4 + reg], part[reg]);
        }
        if (w == 0 && l16 < 6) {
            const float bh = bfc[128 + l16];
            #pragma unroll
            for (int reg = 0; reg < 4; reg++) h6s[quad * 4 + reg][l16] = accH[reg] + bh;
        }
    }
    __syncthreads();

    if (tid < 16) {
        const float kn = sqrtf(ksum[tid]);
        const float* h = h6s[tid];
        const float beta = softplus_f(h[0]);
        const float g = 1.f / (1.f + __expf(-h[1]));
        const float m3 = fmaxf(h[2], fmaxf(h[3], h[4]));
        const float e0 = __expf(h[2] - m3), e1 = __expf(h[3] - m3), e2 = __expf(h[4] - m3);
        const float inv = 1.f / (e0 + e1 + e2);
        scal_s[tid][0] = beta / kn;
        scal_s[tid][1] = g;
        scal_s[tid][2] = e0 * inv;
        scal_s[tid][3] = e1 * inv;
        scal_s[tid][4] = e2 * inv;
        scal_s[tid][5] = 1.f + softplus_f(h[5]);
    }
    __syncthreads();

    // ---- phase 1: E = exp((beta/kn)*(1/mn)*(k . M_i)), distance-2 prefetch --
    {
        float cbs[4];
        #pragma unroll
        for (int reg = 0; reg < 4; reg++) cbs[reg] = scal_s[quad * 4 + reg][0];

        const bf16x8 af0 = *(const bf16x8*)&k_s[l16][quad * 8];
        const bf16x8 af1 = *(const bf16x8*)&k_s[l16][32 + quad * 8];
        const bf16x8 af2 = *(const bf16x8*)&k_s[l16][64 + quad * 8];
        const bf16x8 af3 = *(const bf16x8*)&k_s[l16][96 + quad * 8];

        const unsigned short* bpw = Mb_sw + (size_t)(w * 16) * 2048 + lane * 8;
        bf16x8 f00 = *(const bf16x8*)(bpw);
        bf16x8 f01 = *(const bf16x8*)(bpw + 512);
        bf16x8 f02 = *(const bf16x8*)(bpw + 1024);
        bf16x8 f03 = *(const bf16x8*)(bpw + 1536);
        bf16x8 f10 = *(const bf16x8*)(bpw + 2048);
        bf16x8 f11 = *(const bf16x8*)(bpw + 2048 + 512);
        bf16x8 f12 = *(const bf16x8*)(bpw + 2048 + 1024);
        bf16x8 f13 = *(const bf16x8*)(bpw + 2048 + 1536);
        float im0 = imn[(w * 16 + 0) * 16 + l16];
        float im1 = imn[(w * 16 + 1) * 16 + l16];

        float Sp[4] = {0.f, 0.f, 0.f, 0.f};
        #pragma unroll
        for (int t = 0; t < 16; t += 2) {
            // ---- even sub-iter: row tile nt = w*16+t, slot 0 ----
            {
                const int nt = w * 16 + t;
                f32x4 aA = {0.f, 0.f, 0.f, 0.f};
                f32x4 aB = {0.f, 0.f, 0.f, 0.f};
                aA = __builtin_amdgcn_mfma_f32_16x16x32_bf16(af0, f00, aA, 0, 0, 0);
                aB = __builtin_amdgcn_mfma_f32_16x16x32_bf16(af2, f02, aB, 0, 0, 0);
                aA = __builtin_amdgcn_mfma_f32_16x16x32_bf16(af1, f01, aA, 0, 0, 0);
                aB = __builtin_amdgcn_mfma_f32_16x16x32_bf16(af3, f03, aB, 0, 0, 0);
                const float imc = im0;
                if (t < 14) {   // prefetch row tile nt+2 into slot 0
                    const unsigned short* bp = Mb_sw + (size_t)(nt + 2) * 2048 + lane * 8;
                    f00 = *(const bf16x8*)(bp);
                    f01 = *(const bf16x8*)(bp + 512);
                    f02 = *(const bf16x8*)(bp + 1024);
                    f03 = *(const bf16x8*)(bp + 1536);
                    im0 = imn[(nt + 2) * 16 + l16];
                }
                const int n0 = nt * 16;
                #pragma unroll
                for (int reg = 0; reg < 4; reg++) {
                    const float e = __expf((aA[reg] + aB[reg]) * cbs[reg] * imc);
                    E_s[quad * 4 + reg][n0 + l16] = f2bf(e);
                    Sp[reg] += e;
                }
            }
            // ---- odd sub-iter: row tile nt = w*16+t+1, slot 1 ----
            {
                const int nt = w * 16 + t + 1;
                f32x4 aA = {0.f, 0.f, 0.f, 0.f};
                f32x4 aB = {0.f, 0.f, 0.f, 0.f};
                aA = __builtin_amdgcn_mfma_f32_16x16x32_bf16(af0, f10, aA, 0, 0, 0);
                aB = __builtin_amdgcn_mfma_f32_16x16x32_bf16(af2, f12, aB, 0, 0, 0);
                aA = __builtin_amdgcn_mfma_f32_16x16x32_bf16(af1, f11, aA, 0, 0, 0);
                aB = __builtin_amdgcn_mfma_f32_16x16x32_bf16(af3, f13, aB, 0, 0, 0);
                const float imc = im1;
                if (t < 13) {   // prefetch row tile nt+2 = w*16+t+3 into slot 1
                    const unsigned short* bp = Mb_sw + (size_t)(nt + 2) * 2048 + lane * 8;
                    f10 = *(const bf16x8*)(bp);
                    f11 = *(const bf16x8*)(bp + 512);
                    f12 = *(const bf16x8*)(bp + 1024);
                    f13 = *(const bf16x8*)(bp + 1536);
                    im1 = imn[(nt + 2) * 16 + l16];
                }
                const int n0 = nt * 16;
                #pragma unroll
                for (int reg = 0; reg < 4; reg++) {
                    const float e = __expf((aA[reg] + aB[reg]) * cbs[reg] * imc);
                    E_s[quad * 4 + reg][n0 + l16] = f2bf(e);
                    Sp[reg] += e;
                }
            }
        }
        #pragma unroll
        for (int s = 1; s < 16; s <<= 1) {
            #pragma unroll
            for (int reg = 0; reg < 4; reg++) Sp[reg] += __shfl_xor(Sp[reg], s);
        }
        if (l16 == 0) {
            #pragma unroll
            for (int reg = 0; reg < 4; reg++) wred[quad * 4 + reg][w] = Sp[reg];
        }
    }
    __syncthreads();
    if (tid < 16) {
        float S = 0.f;
        #pragma unroll
        for (int i = 0; i < 8; i++) S += wred[tid][i];
        const float g = scal_s[tid][1];
        fa_s[tid] = g / S;
        fc_s[tid] = 1.f - g;
    }
    __syncthreads();

    // ---- phase 1.5: parallel shift+pow, in place; wprev all in registers ----
    // Row prow owned by a 32-lane half-wave; lane pg owns chunks (pg+32j)*8.
    // wprev chunks j=0..3 held since kernel entry; j+4 prefetched at iter j
    // (distance 4 >= HBM latency). Edges via __shfl of neighbor chunks
    // (identical floats to the old scalar loads -> bit-identical output):
    //   wpR(g,j) = lane g+1's wac.x | g==31: lane0's chunk j+1 .x | j==7: Wsav
    //   wpL(g,j) = lane g-1's wbc.w | g==0: carryW (lane31 prev chunk) | j==0: wpL0
    {
        const float s0 = scal_s[prow][2], s1 = scal_s[prow][3], s2 = scal_s[prow][4];
        const float gmm = scal_s[prow][5];
        const float fa = fa_s[prow], fcm = fc_s[prow];

        const float Wsav = __shfl(wva[0].x, pbase);   // lane0 chunk0 .x (j==7 wrap)
        float carryW = 0.f;

        int c0 = pc0;
        bf16x8 E8c = *(const bf16x8*)&E_s[prow][c0];
        float eLc  = bf2f(E_s[prow][(c0 + NR - 1) & (NR - 1)]);
        float eRc  = bf2f(E_s[prow][c0 + 8]);

        float Zp = 0.f, carry = 0.f, E0sav = 0.f;
        #pragma unroll
        for (int j = 0; j < 8; j++) {
            const int sl = j & 3;
            const float4 wac = wva[sl];
            const float4 wbc = wvb[sl];

            bf16x8 E8n; float eLn = 0.f, eRn = 0.f;
            if (j < 7) {                       // E prefetch j+1 (before store!)
                const int c1 = c0 + 256;
                E8n = *(const bf16x8*)&E_s[prow][c1];
                eLn = bf2f(E_s[prow][c1 - 1]);
                eRn = bf2f(E_s[prow][(c1 + 8) & (NR - 1)]);
            }

            // wprev edges from registers via shfl
            const float shR = __shfl(wac.x, pbase + ((pg + 1) & 31));
            const float shL = __shfl(wbc.w, pbase + ((pg + 31) & 31));
            float rnext = 0.f;
            if (j < 7) rnext = __shfl(wva[(j + 1) & 3].x, pbase);  // lane0 chunk j+1
            const float wpRc = (pg == 31) ? ((j == 7) ? Wsav : rnext) : shR;
            const float wpLc = (j == 0) ? wpL0 : ((pg == 0) ? carryW : shL);
            carryW = __shfl(wbc.w, pbase + 31);

            if (j < 4) {                       // prefetch chunk j+4 into slot sl
                wva[sl] = *(const float4*)(wp + c0 + 1024);
                wvb[sl] = *(const float4*)(wp + c0 + 1024 + 4);
            }

            float ef[8];
            #pragma unroll
            for (int i = 0; i < 8; i++) ef[i] = bf2f((unsigned short)E8c[i]);
            if (j == 0) E0sav = __shfl(ef[0], pbase);
            const float eL = (pg == 0 && j > 0) ? carry : eLc;
            const float eR = (pg == 31 && j == 7) ? E0sav : eRc;
            carry = __shfl(ef[7], pbase + 31);

            float wg[10];
            wg[0] = fmaf(fa, eL,    fcm * wpLc);
            wg[1] = fmaf(fa, ef[0], fcm * wac.x);
            wg[2] = fmaf(fa, ef[1], fcm * wac.y);
            wg[3] = fmaf(fa, ef[2], fcm * wac.z);
            wg[4] = fmaf(fa, ef[3], fcm * wac.w);
            wg[5] = fmaf(fa, ef[4], fcm * wbc.x);
            wg[6] = fmaf(fa, ef[5], fcm * wbc.y);
            wg[7] = fmaf(fa, ef[6], fcm * wbc.z);
            wg[8] = fmaf(fa, ef[7], fcm * wbc.w);
            wg[9] = fmaf(fa, eR,    fcm * wpRc);

            bf16x8 out8;
            #pragma unroll
            for (int i = 0; i < 8; i++) {
                const float wt = fmaf(s0, wg[i], fmaf(s1, wg[i + 1], s2 * wg[i + 2])) + EPSF;
                const float pw = exp2f(gmm * log2f(wt));   // wt^gamma, wt > 0
                Zp += pw;
                out8[i] = (short)f2bf(pw);
            }
            *(bf16x8*)&E_s[prow][c0] = out8;

            c0 += 256;
            E8c = E8n; eLc = eLn; eRc = eRn;
        }
        #pragma unroll
        for (int s = 1; s < 32; s <<= 1) Zp += __shfl_xor(Zp, s);
        if (pg == 0) invZ_s[prow] = 1.f / Zp;
    }
    __syncthreads();

    // ---- phase 2: r = (w_pow @ M) * invZ, distance-2 Mt_sw prefetch -------
    {
        f32x4 acc0 = {0.f, 0.f, 0.f, 0.f};
        f32x4 acc1 = {0.f, 0.f, 0.f, 0.f};
        f32x4 acc2 = {0.f, 0.f, 0.f, 0.f};
        f32x4 acc3 = {0.f, 0.f, 0.f, 0.f};
        const unsigned short* bp = Mt_sw + (size_t)w * 32768 + lane * 8;
        bf16x8 c00 = *(const bf16x8*)(bp);
        bf16x8 c01 = *(const bf16x8*)(bp + 512);
        bf16x8 c02 = *(const bf16x8*)(bp + 1024);
        bf16x8 c03 = *(const bf16x8*)(bp + 1536);
        bf16x8 c10 = *(const bf16x8*)(bp + 2048);
        bf16x8 c11 = *(const bf16x8*)(bp + 2048 + 512);
        bf16x8 c12 = *(const bf16x8*)(bp + 2048 + 1024);
        bf16x8 c13 = *(const bf16x8*)(bp + 2048 + 1536);

        #pragma unroll
        for (int k0 = 0; k0 < NR; k0 += 256) {
            // ---- even half: A at columns k0..k0+127, B chunks (k0>>5)..+3 --
            {
                const bf16x8 a0 = *(const bf16x8*)&E_s[l16][k0 + quad * 8];
                const bf16x8 a1 = *(const bf16x8*)&E_s[l16][k0 + 32 + quad * 8];
                const bf16x8 a2 = *(const bf16x8*)&E_s[l16][k0 + 64 + quad * 8];
                const bf16x8 a3 = *(const bf16x8*)&E_s[l16][k0 + 96 + quad * 8];
                acc0 = __builtin_amdgcn_mfma_f32_16x16x32_bf16(a0, c00, acc0, 0, 0, 0);
                acc1 = __builtin_amdgcn_mfma_f32_16x16x32_bf16(a1, c01, acc1, 0, 0, 0);
                acc2 = __builtin_amdgcn_mfma_f32_16x16x32_bf16(a2, c02, acc2, 0, 0, 0);
                acc3 = __builtin_amdgcn_mfma_f32_16x16x32_bf16(a3, c03, acc3, 0, 0, 0);
                if (k0 < NR - 256) {   // prefetch chunks for k0+256 into slot 0
                    const unsigned short* np = bp + (size_t)((k0 >> 5) + 8) * 512;
                    c00 = *(const bf16x8*)(np);
                    c01 = *(const bf16x8*)(np + 512);
                    c02 = *(const bf16x8*)(np + 1024);
                    c03 = *(const bf16x8*)(np + 1536);
                }
            }
            // ---- odd half: A at columns k0+128.., B chunks (k0>>5)+4..+7 ---
            {
                const int k1 = k0 + 128;
                const bf16x8 a0 = *(const bf16x8*)&E_s[l16][k1 + quad * 8];
                const bf16x8 a1 = *(const bf16x8*)&E_s[l16][k1 + 32 + quad * 8];
                const bf16x8 a2 = *(const bf16x8*)&E_s[l16][k1 + 64 + quad * 8];
                const bf16x8 a3 = *(const bf16x8*)&E_s[l16][k1 + 96 + quad * 8];
                acc0 = __builtin_amdgcn_mfma_f32_16x16x32_bf16(a0, c10, acc0, 0, 0, 0);
                acc1 = __builtin_amdgcn_mfma_f32_16x16x32_bf16(a1, c11, acc1, 0, 0, 0);
                acc2 = __builtin_amdgcn_mfma_f32_16x16x32_bf16(a2, c12, acc2, 0, 0, 0);
                acc3 = __builtin_amdgcn_mfma_f32_16x16x32_bf16(a3, c13, acc3, 0, 0, 0);
                if (k0 < NR - 384) {   // prefetch chunks for k1+256 into slot 1
                    const unsigned short* np = bp + (size_t)((k0 >> 5) + 12) * 512;
                    c10 = *(const bf16x8*)(np);
                    c11 = *(const bf16x8*)(np + 512);
                    c12 = *(const bf16x8*)(np + 1024);
                    c13 = *(const bf16x8*)(np + 1536);
                }
            }
        }
        #pragma unroll
        for (int reg = 0; reg < 4; reg++) {
            const int m = quad * 4 + reg;
            const float v = (acc0[reg] + acc1[reg]) + (acc2[reg] + acc3[reg]);
            out[(size_t)(b0 + m) * NC + w * 16 + l16] = v * invZ_s[m];
        }
    }
}

extern "C" void kernel_launch(void* const* d_in, const int* in_sizes, int n_in,
                              void* d_out, int out_size, void* d_ws, size_t ws_size,
                              hipStream_t stream) {
    const float* x     = (const float*)d_in[0];
    const float* Wfc   = (const float*)d_in[1];
    const float* bfc   = (const float*)d_in[2];
    const float* M     = (const float*)d_in[3];
    const float* wprev = (const float*)d_in[4];
    float* out = (float*)d_out;

    char* ws = (char*)d_ws;
    float*          imn   = (float*)(ws);                      // 8192 B
    unsigned short* Mb_sw = (unsigned short*)(ws + 8192);      // 524288 B
    unsigned short* Mt_sw = (unsigned short*)(ws + 532480);    // 524288 B
    unsigned short* Wt_sw = (unsigned short*)(ws + 1056768);   // 294912 B

    hipLaunchKernelGGL(prep_all, dim3(NR + KCTRL), dim3(64), 0, stream,
                       M, Mb_sw, Mt_sw, imn, Wfc, Wt_sw);
    hipLaunchKernelGGL(fused_ntm, dim3(NB / 16), dim3(512), 0, stream,
                       x, Wt_sw, bfc, Mb_sw, Mt_sw, imn, wprev, out);
}